// Round 16
// baseline (193.456 us; speedup 1.0000x reference)
//
#include <hip/hip_runtime.h>

#define T_TOKENS 8192
#define D_MODEL  4096
#define N_EXP    64
#define BT       16           // tokens per fused block
#define NBLK     (T_TOKENS / BT)   // 512 blocks
#define TAU      1e-6f        // gap threshold for f64 repair (~8 sigma of split-bf16 err)

typedef __attribute__((ext_vector_type(8))) short bf16x8;   // 8 bf16 (4 VGPR)
typedef __attribute__((ext_vector_type(4))) float f32x4;

#define MFMA(A,B,C) __builtin_amdgcn_mfma_f32_16x16x32_bf16(A, B, C, 0, 0, 0)

__device__ __forceinline__ unsigned short bf16rne(float x) {
    unsigned u = __float_as_uint(x);
    return (unsigned short)((u + 0x7FFFu + ((u >> 16) & 1u)) >> 16);
}
__device__ __forceinline__ unsigned pack2(float a, float b, float& ra, float& rb) {
    unsigned short ha = bf16rne(a), hb = bf16rne(b);
    ra = a - __uint_as_float((unsigned)ha << 16);
    rb = b - __uint_as_float((unsigned)hb << 16);
    return (unsigned)ha | ((unsigned)hb << 16);
}
__device__ __forceinline__ void cvt8(const float4& a, const float4& b,
                                     uint4& hi, uint4& lo) {
    float r0,r1,r2,r3,r4,r5,r6,r7;
    hi.x = pack2(a.x, a.y, r0, r1);
    hi.y = pack2(a.z, a.w, r2, r3);
    hi.z = pack2(b.x, b.y, r4, r5);
    hi.w = pack2(b.z, b.w, r6, r7);
    lo.x = (unsigned)bf16rne(r0) | ((unsigned)bf16rne(r1) << 16);
    lo.y = (unsigned)bf16rne(r2) | ((unsigned)bf16rne(r3) << 16);
    lo.z = (unsigned)bf16rne(r4) | ((unsigned)bf16rne(r5) << 16);
    lo.w = (unsigned)bf16rne(r6) | ((unsigned)bf16rne(r7) << 16);
}
__device__ __forceinline__ unsigned cvt2(const float2 v, unsigned& lo) {
    float r0, r1;
    unsigned hi = pack2(v.x, v.y, r0, r1);
    lo = (unsigned)bf16rne(r0) | ((unsigned)bf16rne(r1) << 16);
    return hi;
}

// ---------------------------------------------------------------------------
// Kernel 1: FUSED split-bf16 MFMA gemm + softmax + top-8 + flags + aux.
// Block = 16 tokens x 64 experts x FULL K (no split-K, no part buffer).
// grid 512 = 2 blocks/CU (TLP; R10: 1 block/CU is latency-poison).
// Wave wv: 16 tok x 16 exp tile, 3 MFMA per 32-k step (hh*wh+hh*wl+hl*wh,
// err sigma ~1.2e-7 << TAU -> flag+repair keeps exact top-k).
// R13's depth-1 LDS double-buffer pipeline. w (1MB) is L2-resident.
// Epilogue: acc -> LDS logits (m89 layout) -> proven router body from LDS.
// Flags: sentinel array flag_list[t] = flg ? t : -1 (no atomics/counter).
// ---------------------------------------------------------------------------
__global__ __launch_bounds__(256) void k_fused(const float* __restrict__ h,
                                               const float* __restrict__ w,
                                               float* __restrict__ out_idx,
                                               float* __restrict__ out_w,
                                               float* __restrict__ expsum,
                                               int* __restrict__ flag_list) {
    __shared__ unsigned short LHS[2][2][BT][40];  // [dbuf][hi/lo][tok][kpad] 5 KB
    __shared__ unsigned short LWS[2][2][64][40];  // 20.5 KB
    __shared__ float slog[BT][66];                // 4.2 KB logits
    __shared__ float laux[4][64];                 // 1 KB
    const int tid  = threadIdx.x;
    const int wv   = tid >> 6;
    const int lane = tid & 63;
    const int lq   = lane >> 4;     // quarter 0..3
    const int lr   = lane & 15;
    const int koff = lq * 8;        // frag k-offset (bf16 elems)
    const int T0   = blockIdx.x * BT;

    // staging: h row = tid>>4 (16 rows x 16 thr), 2 f32/thr; w row = tid&63, 8 f32/thr
    const int hrow = tid >> 4, hcol = (tid & 15) * 2;
    const int wrow = tid & 63, wq = (tid >> 6) * 8;
    const float* gh = h + (size_t)(T0 + hrow) * D_MODEL + hcol;
    const float* gw = w + (size_t)wrow * D_MODEL + wq;

    f32x4 acc = {0.f, 0.f, 0.f, 0.f};
    float2 hv; float4 w0, w1;                     // prefetch regs
    auto gload = [&](int it) {
        hv = *(const float2*)(gh + it * 32);
        w0 = *(const float4*)(gw + it * 32);
        w1 = *(const float4*)(gw + it * 32 + 4);
    };
    auto writebuf = [&](int nb) {
        unsigned lo2, hi2 = cvt2(hv, lo2);
        *(unsigned*)&LHS[nb][0][hrow][hcol] = hi2;
        *(unsigned*)&LHS[nb][1][hrow][hcol] = lo2;
        uint4 hi, lo; cvt8(w0, w1, hi, lo);
        *(uint4*)&LWS[nb][0][wrow][wq] = hi;
        *(uint4*)&LWS[nb][1][wrow][wq] = lo;
    };

    const int nt = D_MODEL / 32;    // 128 k-tiles
    gload(0); writebuf(0);
    __syncthreads();
    for (int it = 0; it < nt; ++it) {
        const int b = it & 1;
        if (it + 1 < nt) gload(it + 1);           // lands during MFMA phase
        const bf16x8 Bh = *(const bf16x8*)&LWS[b][0][wv * 16 + lr][koff];
        const bf16x8 Bl = *(const bf16x8*)&LWS[b][1][wv * 16 + lr][koff];
        const bf16x8 Ah = *(const bf16x8*)&LHS[b][0][lr][koff];
        const bf16x8 Al = *(const bf16x8*)&LHS[b][1][lr][koff];
        acc = MFMA(Ah, Bh, acc);
        acc = MFMA(Ah, Bl, acc);
        acc = MFMA(Al, Bh, acc);
        if (it + 1 < nt) writebuf(b ^ 1);         // vmcnt wait lands here
        __syncthreads();
    }

    // C/D layout (m89-verified): col(expert) = lane&15, row(token) = (lane>>4)*4+reg
#pragma unroll
    for (int i = 0; i < 4; ++i)
        slog[lq * 4 + i][wv * 16 + lr] = acc[i];
    __syncthreads();

    // router phase: wave wv handles tokens wv*4 .. wv*4+3, lane = expert
    float aux_acc = 0.f;
    for (int tt = 0; tt < 4; ++tt) {
        const int t = wv * 4 + tt, gt = T0 + t;
        const float lg = slog[t][lane];

        float m = lg;
#pragma unroll
        for (int off = 32; off; off >>= 1) m = fmaxf(m, __shfl_xor(m, off));
        const float p = __expf(lg - m);
        float s = p;
#pragma unroll
        for (int off = 32; off; off >>= 1) s += __shfl_xor(s, off);
        const float inv_s = 1.f / s;
        aux_acc += p * inv_s;

        float pv = lg; int pi = lane;
        float myp = 0.f; int myi = 0; float tsum = 0.f, prev = 0.f;
        bool flg = false;
#pragma unroll
        for (int r = 0; r < 9; ++r) {
            float bv = pv; int bi = pi;
#pragma unroll
            for (int off = 32; off; off >>= 1) {
                const float ov = __shfl_xor(bv, off);
                const int   oi = __shfl_xor(bi, off);
                if (ov > bv || (ov == bv && oi < bi)) { bv = ov; bi = oi; }
            }
            if (r > 0) flg = flg || (prev - bv < TAU);
            prev = bv;
            if (r < 8) {
                const float bp = __expf(bv - m) * inv_s;
                tsum += bp;
                if (lane == r)  { myp = bp; myi = bi; }
                if (lane == bi) pv = -1e30f;
            }
        }
        if (lane < 8) {
            out_idx[(size_t)gt * 8 + lane] = (float)myi;
            out_w[(size_t)gt * 8 + lane]   = myp / tsum;
        }
        if (lane == 0) flag_list[gt] = flg ? gt : -1;
    }

    laux[wv][lane] = aux_acc;
    __syncthreads();
    if (tid < 64)
        expsum[(size_t)blockIdx.x * 64 + tid] =
            laux[0][tid] + laux[1][tid] + laux[2][tid] + laux[3][tid];
}

// ---------------------------------------------------------------------------
// Kernel 2: f64 repair. Block b scans tokens [b*16, b*16+16) via sentinel
// flag_list (no counter). Block 0 also finalizes the aux loss.
// ---------------------------------------------------------------------------
__global__ __launch_bounds__(256) void k_repair(const float* __restrict__ h,
                                                const float* __restrict__ w,
                                                const int* __restrict__ flag_list,
                                                float* __restrict__ out_idx,
                                                float* __restrict__ out_w,
                                                const float* __restrict__ expsum,
                                                int nb,
                                                float* __restrict__ out_aux) {
    __shared__ float  sh[D_MODEL];   // 16 KB
    __shared__ double sp[4][64];     //  2 KB
    __shared__ float  lx[4][64];     //  1 KB (aux)
    const int tid  = threadIdx.x;
    const int lane = tid & 63;
    const int c    = tid >> 6;

    if (blockIdx.x == 0) {           // fused aux finalize
        float s = 0.f;
        for (int b = c; b < nb; b += 4) s += expsum[(size_t)b * 64 + lane];
        lx[c][lane] = s;
        __syncthreads();
        if (tid < 64) {
            const float tot = lx[0][lane] + lx[1][lane] + lx[2][lane] + lx[3][lane];
            const float avg = tot * (1.f / (float)T_TOKENS);
            float v = avg * avg;
#pragma unroll
            for (int off = 32; off; off >>= 1) v += __shfl_xor(v, off);
            if (lane == 0) out_aux[0] = (float)N_EXP * 0.001f * v;
        }
    }

    const int t0 = blockIdx.x * BT;
    for (int t = t0; t < t0 + BT; ++t) {
        if (flag_list[t] < 0) continue;          // block-uniform
        __syncthreads();   // previous iteration's readers done
#pragma unroll
        for (int q = 0; q < 4; ++q) {
            const int o = (q * 256 + tid) * 4;
            *reinterpret_cast<float4*>(&sh[o]) =
                *reinterpret_cast<const float4*>(&h[(size_t)t * D_MODEL + o]);
        }
        __syncthreads();

        const float* wp = &w[(size_t)lane * D_MODEL + c * 1024];
        const float* hp = &sh[c * 1024];
        double acc[8] = {0, 0, 0, 0, 0, 0, 0, 0};
        for (int q = 0; q < 32; ++q) {
            float4 wv8[8], hv8[8];
#pragma unroll
            for (int u = 0; u < 8; ++u) {
                wv8[u] = *reinterpret_cast<const float4*>(&wp[(q * 8 + u) * 4]);
                hv8[u] = *reinterpret_cast<const float4*>(&hp[(q * 8 + u) * 4]);
            }
#pragma unroll
            for (int u = 0; u < 8; ++u) {
                acc[u] = fma((double)hv8[u].x, (double)wv8[u].x, acc[u]);
                acc[u] = fma((double)hv8[u].y, (double)wv8[u].y, acc[u]);
                acc[u] = fma((double)hv8[u].z, (double)wv8[u].z, acc[u]);
                acc[u] = fma((double)hv8[u].w, (double)wv8[u].w, acc[u]);
            }
        }
        sp[c][lane] = (((acc[0] + acc[1]) + (acc[2] + acc[3])) +
                       ((acc[4] + acc[5]) + (acc[6] + acc[7])));
        __syncthreads();

        if (tid < 64) {
            const double mylg = ((sp[0][lane] + sp[1][lane]) +
                                 (sp[2][lane] + sp[3][lane]));
            double m = mylg;
#pragma unroll
            for (int off = 32; off; off >>= 1) m = fmax(m, __shfl_xor(m, off));
            double pv = mylg; int pi = lane;
            double myp = 0.0; int myi = 0; double tsum = 0.0;
#pragma unroll
            for (int r = 0; r < 8; ++r) {
                double bv = pv; int bi = pi;
#pragma unroll
                for (int off = 32; off; off >>= 1) {
                    const double ov = __shfl_xor(bv, off);
                    const int    oi = __shfl_xor(bi, off);
                    if (ov > bv || (ov == bv && oi < bi)) { bv = ov; bi = oi; }
                }
                const double bp = exp(bv - m);
                tsum += bp;
                if (lane == r)  { myp = bp; myi = bi; }
                if (lane == bi) pv = -1.0e300;
            }
            if (lane < 8) {
                out_idx[(size_t)t * 8 + lane] = (float)myi;
                out_w[(size_t)t * 8 + lane]   = (float)(myp / tsum);
            }
        }
    }
}

extern "C" void kernel_launch(void* const* d_in, const int* in_sizes, int n_in,
                              void* d_out, int out_size, void* d_ws, size_t ws_size,
                              hipStream_t stream) {
    const float* h = (const float*)d_in[0];   // [8192,4096]
    const float* w = (const float*)d_in[1];   // [64,4096]
    float* out      = (float*)d_out;
    float* out_idx  = out;                    // 65536 (indices as float)
    float* out_w    = out + 65536;            // 65536
    float* out_aux  = out + 131072;           // 1

    float* expsum    = (float*)d_ws;                      // 512*64 f32
    int*   flag_list = (int*)(expsum + (size_t)NBLK * 64);// 8192 ints

    k_fused<<<NBLK, 256, 0, stream>>>(h, w, out_idx, out_w, expsum, flag_list);
    k_repair<<<NBLK, 256, 0, stream>>>(h, w, flag_list, out_idx, out_w,
                                       expsum, NBLK, out_aux);
}

// Round 17
// 136.997 us; speedup vs baseline: 1.4121x; 1.4121x over previous
//
#include <hip/hip_runtime.h>

#define T_TOKENS 8192
#define D_MODEL  4096
#define N_EXP    64
#define TAU      1e-6f        // gap threshold for f64 repair (~8 sigma of split-bf16 err)

typedef __attribute__((ext_vector_type(8))) short bf16x8;   // 8 bf16 (4 VGPR)
typedef __attribute__((ext_vector_type(4))) float f32x4;

#define MFMA(A,B,C) __builtin_amdgcn_mfma_f32_16x16x32_bf16(A, B, C, 0, 0, 0)

__device__ __forceinline__ unsigned short bf16rne(float x) {
    unsigned u = __float_as_uint(x);
    return (unsigned short)((u + 0x7FFFu + ((u >> 16) & 1u)) >> 16);
}
__device__ __forceinline__ unsigned pack2(float a, float b, float& ra, float& rb) {
    unsigned short ha = bf16rne(a), hb = bf16rne(b);
    ra = a - __uint_as_float((unsigned)ha << 16);
    rb = b - __uint_as_float((unsigned)hb << 16);
    return (unsigned)ha | ((unsigned)hb << 16);
}
__device__ __forceinline__ void cvt8(const float4& a, const float4& b,
                                     uint4& hi, uint4& lo) {
    float r0,r1,r2,r3,r4,r5,r6,r7;
    hi.x = pack2(a.x, a.y, r0, r1);
    hi.y = pack2(a.z, a.w, r2, r3);
    hi.z = pack2(b.x, b.y, r4, r5);
    hi.w = pack2(b.z, b.w, r6, r7);
    lo.x = (unsigned)bf16rne(r0) | ((unsigned)bf16rne(r1) << 16);
    lo.y = (unsigned)bf16rne(r2) | ((unsigned)bf16rne(r3) << 16);
    lo.z = (unsigned)bf16rne(r4) | ((unsigned)bf16rne(r5) << 16);
    lo.w = (unsigned)bf16rne(r6) | ((unsigned)bf16rne(r7) << 16);
}

// ---------------------------------------------------------------------------
// Kernel 1: split-bf16 MFMA partial GEMM (hh*wh + hh*wl + hl*wh; err sigma
// ~1.2e-7 << TAU -> flag+repair keeps exact top-k). R15 structure with
// 64-token blocks: grid (128, KS=8) = 1024 blocks = 4/CU (was 2/CU), LDS
// 40KB. Wave = 16 tok x 64 exp: 12 MFMA + 10 ds_read_b128 per 32-k step.
// Same 16-tile K-chain, depth-1 LDS double-buffer, m89 C/D epilogue.
// R16 lesson: K-chain must stay short (128 serial tiles = 165us disaster).
// ---------------------------------------------------------------------------
__global__ __launch_bounds__(256) void k_gemm(const float* __restrict__ h,
                                              const float* __restrict__ w,
                                              float* __restrict__ part,
                                              int ks_len,
                                              int* __restrict__ flag_cnt) {
    __shared__ unsigned short LHS[2][2][64][40];  // [dbuf][hi/lo][tok][kpad] 20 KB
    __shared__ unsigned short LWS[2][2][64][40];  // 20 KB => 40 KB total
    const int tid  = threadIdx.x;
    const int wv   = tid >> 6;
    const int lane = tid & 63;
    const int T0   = blockIdx.x * 64;
    const int k0   = blockIdx.y * ks_len;
    const int lq   = lane >> 4;     // quarter 0..3
    const int lr   = lane & 15;
    const int koff = lq * 8;        // frag k-offset (bf16 elems)

    if (blockIdx.x == 0 && blockIdx.y == 0 && tid == 0) *flag_cnt = 0;

    // staging: h/w row = tid&63, 8-f32 quarter = (tid>>6)*8
    const int srow = tid & 63, sq = (tid >> 6) * 8;
    const float* gh = h + (size_t)(T0 + srow) * D_MODEL + k0 + sq;
    const float* gw = w + (size_t)srow * D_MODEL + k0 + sq;

    f32x4 acc[4];
#pragma unroll
    for (int j = 0; j < 4; ++j)
#pragma unroll
        for (int x = 0; x < 4; ++x) acc[j][x] = 0.f;

    float4 h0, h1, w0, w1;              // prefetch regs (static names)
    auto gload = [&](int it) {
        const float* p = gh + it * 32;
        h0 = *(const float4*)(p);      h1 = *(const float4*)(p + 4);
        const float* q = gw + it * 32;
        w0 = *(const float4*)(q);      w1 = *(const float4*)(q + 4);
    };
    auto writebuf = [&](int nb) {
        uint4 hi, lo;
        cvt8(h0, h1, hi, lo);
        *(uint4*)&LHS[nb][0][srow][sq] = hi;
        *(uint4*)&LHS[nb][1][srow][sq] = lo;
        cvt8(w0, w1, hi, lo);
        *(uint4*)&LWS[nb][0][srow][sq] = hi;
        *(uint4*)&LWS[nb][1][srow][sq] = lo;
    };

    const int nt = ks_len >> 5;         // 16 tiles at KS=8
    gload(0);
    writebuf(0);
    __syncthreads();
    for (int it = 0; it < nt; ++it) {
        const int b = it & 1;
        if (it + 1 < nt) gload(it + 1);             // lands during MFMA phase
        const bf16x8 Ah = *(const bf16x8*)&LHS[b][0][wv * 16 + lr][koff];
        const bf16x8 Al = *(const bf16x8*)&LHS[b][1][wv * 16 + lr][koff];
#pragma unroll
        for (int j = 0; j < 4; ++j) {
            const bf16x8 Bh = *(const bf16x8*)&LWS[b][0][j * 16 + lr][koff];
            const bf16x8 Bl = *(const bf16x8*)&LWS[b][1][j * 16 + lr][koff];
            acc[j] = MFMA(Ah, Bh, acc[j]);
            acc[j] = MFMA(Ah, Bl, acc[j]);
            acc[j] = MFMA(Al, Bh, acc[j]);
        }
        if (it + 1 < nt) writebuf(b ^ 1);           // vmcnt wait lands here
        __syncthreads();
    }

    // C/D layout (m89-verified): col(token)=lane&15? No: A=token frag ->
    // D col = lane&15 indexes B-rows? Same convention as R12-R15:
    // token t = wave's A-tile row = lq*4+i ; expert e = j*16 + lr.
    float* pb = part + (size_t)blockIdx.y * T_TOKENS * N_EXP;
#pragma unroll
    for (int j = 0; j < 4; ++j)
#pragma unroll
        for (int i = 0; i < 4; ++i) {
            const int t = T0 + wv * 16 + lq * 4 + i;
            const int e = j * 16 + lr;
            pb[(size_t)t * N_EXP + e] = acc[j][i];
        }
}

// ---------------------------------------------------------------------------
// Kernel 2: per-token softmax + top-8 + gap-based tie flagging + aux partials.
// block 256 (4 waves), wave handles 4 tokens, lane = expert. f32 throughout.
// ---------------------------------------------------------------------------
__global__ __launch_bounds__(256) void k_router(const float* __restrict__ part, int KS,
                                                float* __restrict__ out_idx,
                                                float* __restrict__ out_w,
                                                float* __restrict__ expsum,
                                                int* __restrict__ flag_cnt,
                                                int* __restrict__ flag_list) {
    __shared__ float laux[4][64];
    const int lane = threadIdx.x & 63;
    const int wid  = threadIdx.x >> 6;
    float aux_acc = 0.f;
    const int tbase = blockIdx.x * 16 + wid * 4;
    const size_t kstride = (size_t)T_TOKENS * N_EXP;

    for (int tt = 0; tt < 4; ++tt) {
        const int t = tbase + tt;
        const float* pb = part + (size_t)t * N_EXP + lane;
        float a0 = 0.f, a1 = 0.f, a2 = 0.f, a3 = 0.f;
        int ksi = 0;
        for (; ksi + 4 <= KS; ksi += 4) {
            a0 += pb[(size_t)(ksi + 0) * kstride];
            a1 += pb[(size_t)(ksi + 1) * kstride];
            a2 += pb[(size_t)(ksi + 2) * kstride];
            a3 += pb[(size_t)(ksi + 3) * kstride];
        }
        for (; ksi < KS; ++ksi) a0 += pb[(size_t)ksi * kstride];
        const float lg = (a0 + a1) + (a2 + a3);

        float m = lg;
#pragma unroll
        for (int off = 32; off; off >>= 1) m = fmaxf(m, __shfl_xor(m, off));
        const float p = __expf(lg - m);
        float s = p;
#pragma unroll
        for (int off = 32; off; off >>= 1) s += __shfl_xor(s, off);
        const float inv_s = 1.f / s;
        aux_acc += p * inv_s;

        float pv = lg; int pi = lane;
        float myp = 0.f; int myi = 0; float tsum = 0.f, prev = 0.f;
        bool flg = false;
#pragma unroll
        for (int r = 0; r < 9; ++r) {
            float bv = pv; int bi = pi;
#pragma unroll
            for (int off = 32; off; off >>= 1) {
                const float ov = __shfl_xor(bv, off);
                const int   oi = __shfl_xor(bi, off);
                if (ov > bv || (ov == bv && oi < bi)) { bv = ov; bi = oi; }
            }
            if (r > 0) flg = flg || (prev - bv < TAU);
            prev = bv;
            if (r < 8) {
                const float bp = __expf(bv - m) * inv_s;
                tsum += bp;
                if (lane == r)  { myp = bp; myi = bi; }
                if (lane == bi) pv = -1e30f;
            }
        }
        if (lane < 8) {
            out_idx[(size_t)t * 8 + lane] = (float)myi;
            out_w[(size_t)t * 8 + lane]   = myp / tsum;
        }
        if (lane == 0 && flg) {
            const int pos = atomicAdd(flag_cnt, 1);
            if (pos < T_TOKENS) flag_list[pos] = t;
        }
    }

    laux[wid][lane] = aux_acc;
    __syncthreads();
    if (threadIdx.x < 64)
        expsum[(size_t)blockIdx.x * 64 + threadIdx.x] =
            laux[0][threadIdx.x] + laux[1][threadIdx.x] +
            laux[2][threadIdx.x] + laux[3][threadIdx.x];
}

// ---------------------------------------------------------------------------
// Kernel 3: f64 repair (one block per flagged token) + FUSED aux finalize.
// ---------------------------------------------------------------------------
__global__ __launch_bounds__(256) void k_repair(const float* __restrict__ h,
                                                const float* __restrict__ w,
                                                const int* __restrict__ flag_cnt,
                                                const int* __restrict__ flag_list,
                                                float* __restrict__ out_idx,
                                                float* __restrict__ out_w,
                                                const float* __restrict__ expsum,
                                                int nb,
                                                float* __restrict__ out_aux) {
    __shared__ float  sh[D_MODEL];   // 16 KB
    __shared__ double sp[4][64];     //  2 KB
    __shared__ float  lx[4][64];     //  1 KB (aux)
    const int tid  = threadIdx.x;
    const int lane = tid & 63;
    const int c    = tid >> 6;

    if (blockIdx.x == 0) {           // fused aux finalize
        float s = 0.f;
        for (int b = c; b < nb; b += 4) s += expsum[(size_t)b * 64 + lane];
        lx[c][lane] = s;
        __syncthreads();
        if (tid < 64) {
            const float tot = lx[0][lane] + lx[1][lane] + lx[2][lane] + lx[3][lane];
            const float avg = tot * (1.f / (float)T_TOKENS);
            float v = avg * avg;
#pragma unroll
            for (int off = 32; off; off >>= 1) v += __shfl_xor(v, off);
            if (lane == 0) out_aux[0] = (float)N_EXP * 0.001f * v;
        }
    }

    const int n = min(*flag_cnt, T_TOKENS);
    for (int i = blockIdx.x; i < n; i += gridDim.x) {
        const int t = flag_list[i];
        __syncthreads();   // previous iteration's readers done
#pragma unroll
        for (int q = 0; q < 4; ++q) {
            const int o = (q * 256 + tid) * 4;
            *reinterpret_cast<float4*>(&sh[o]) =
                *reinterpret_cast<const float4*>(&h[(size_t)t * D_MODEL + o]);
        }
        __syncthreads();

        const float* wp = &w[(size_t)lane * D_MODEL + c * 1024];
        const float* hp = &sh[c * 1024];
        double acc[8] = {0, 0, 0, 0, 0, 0, 0, 0};
        for (int q = 0; q < 32; ++q) {
            float4 wv8[8], hv8[8];
#pragma unroll
            for (int u = 0; u < 8; ++u) {
                wv8[u] = *reinterpret_cast<const float4*>(&wp[(q * 8 + u) * 4]);
                hv8[u] = *reinterpret_cast<const float4*>(&hp[(q * 8 + u) * 4]);
            }
#pragma unroll
            for (int u = 0; u < 8; ++u) {
                acc[u] = fma((double)hv8[u].x, (double)wv8[u].x, acc[u]);
                acc[u] = fma((double)hv8[u].y, (double)wv8[u].y, acc[u]);
                acc[u] = fma((double)hv8[u].z, (double)wv8[u].z, acc[u]);
                acc[u] = fma((double)hv8[u].w, (double)wv8[u].w, acc[u]);
            }
        }
        sp[c][lane] = (((acc[0] + acc[1]) + (acc[2] + acc[3])) +
                       ((acc[4] + acc[5]) + (acc[6] + acc[7])));
        __syncthreads();

        if (tid < 64) {
            const double mylg = ((sp[0][lane] + sp[1][lane]) +
                                 (sp[2][lane] + sp[3][lane]));
            double m = mylg;
#pragma unroll
            for (int off = 32; off; off >>= 1) m = fmax(m, __shfl_xor(m, off));
            double pv = mylg; int pi = lane;
            double myp = 0.0; int myi = 0; double tsum = 0.0;
#pragma unroll
            for (int r = 0; r < 8; ++r) {
                double bv = pv; int bi = pi;
#pragma unroll
                for (int off = 32; off; off >>= 1) {
                    const double ov = __shfl_xor(bv, off);
                    const int    oi = __shfl_xor(bi, off);
                    if (ov > bv || (ov == bv && oi < bi)) { bv = ov; bi = oi; }
                }
                const double bp = exp(bv - m);
                tsum += bp;
                if (lane == r)  { myp = bp; myi = bi; }
                if (lane == bi) pv = -1.0e300;
            }
            if (lane < 8) {
                out_idx[(size_t)t * 8 + lane] = (float)myi;
                out_w[(size_t)t * 8 + lane]   = (float)(myp / tsum);
            }
        }
    }
}

extern "C" void kernel_launch(void* const* d_in, const int* in_sizes, int n_in,
                              void* d_out, int out_size, void* d_ws, size_t ws_size,
                              hipStream_t stream) {
    const float* h = (const float*)d_in[0];   // [8192,4096]
    const float* w = (const float*)d_in[1];   // [64,4096]
    float* out      = (float*)d_out;
    float* out_idx  = out;                    // 65536 (indices as float)
    float* out_w    = out + 65536;            // 65536
    float* out_aux  = out + 131072;           // 1

    const size_t part_elems = (size_t)T_TOKENS * N_EXP;
    const int NB2 = 512;
    int KS = 8;                               // grid (128,8)=1024 blocks = 4/CU
    while (KS > 1 &&
           ((size_t)KS * part_elems * 4 + (size_t)NB2 * 64 * 4 +
            4 + (size_t)T_TOKENS * 4) > ws_size)
        KS >>= 1;

    float* part     = (float*)d_ws;
    float* expsum   = part + (size_t)KS * part_elems;
    int*   flag_cnt = (int*)(expsum + (size_t)NB2 * 64);
    int*   flag_list= flag_cnt + 1;

    dim3 g1(T_TOKENS / 64, KS);
    k_gemm<<<g1, 256, 0, stream>>>(h, w, part, D_MODEL / KS, flag_cnt);
    k_router<<<NB2, 256, 0, stream>>>(part, KS, out_idx, out_w, expsum,
                                      flag_cnt, flag_list);
    k_repair<<<512, 256, 0, stream>>>(h, w, flag_cnt, flag_list, out_idx, out_w,
                                      expsum, NB2, out_aux);
}

// Round 18
// 132.532 us; speedup vs baseline: 1.4597x; 1.0337x over previous
//
#include <hip/hip_runtime.h>

#define T_TOKENS 8192
#define D_MODEL  4096
#define N_EXP    64
#define TAU      1e-6f        // gap threshold for f64 repair (~8 sigma of split-bf16 err)

typedef __attribute__((ext_vector_type(8))) short bf16x8;   // 8 bf16 (4 VGPR)
typedef __attribute__((ext_vector_type(4))) float f32x4;

#define MFMA(A,B,C) __builtin_amdgcn_mfma_f32_16x16x32_bf16(A, B, C, 0, 0, 0)

__device__ __forceinline__ unsigned short bf16rne(float x) {
    unsigned u = __float_as_uint(x);
    return (unsigned short)((u + 0x7FFFu + ((u >> 16) & 1u)) >> 16);
}
__device__ __forceinline__ unsigned pack2(float a, float b, float& ra, float& rb) {
    unsigned short ha = bf16rne(a), hb = bf16rne(b);
    ra = a - __uint_as_float((unsigned)ha << 16);
    rb = b - __uint_as_float((unsigned)hb << 16);
    return (unsigned)ha | ((unsigned)hb << 16);
}
__device__ __forceinline__ void cvt8(const float4& a, const float4& b,
                                     uint4& hi, uint4& lo) {
    float r0,r1,r2,r3,r4,r5,r6,r7;
    hi.x = pack2(a.x, a.y, r0, r1);
    hi.y = pack2(a.z, a.w, r2, r3);
    hi.z = pack2(b.x, b.y, r4, r5);
    hi.w = pack2(b.z, b.w, r6, r7);
    lo.x = (unsigned)bf16rne(r0) | ((unsigned)bf16rne(r1) << 16);
    lo.y = (unsigned)bf16rne(r2) | ((unsigned)bf16rne(r3) << 16);
    lo.z = (unsigned)bf16rne(r4) | ((unsigned)bf16rne(r5) << 16);
    lo.w = (unsigned)bf16rne(r6) | ((unsigned)bf16rne(r7) << 16);
}

// ---------------------------------------------------------------------------
// Kernel 1: split-bf16 MFMA partial GEMM (hh*wh + hh*wl + hl*wh; err sigma
// ~1.2e-7 << TAU window -> flag+repair keeps exact top-k). R15's exact
// configuration: 128-token blocks, grid (64, KS=8) = 512 = 2 blocks/CU,
// 60 KB LDS, depth-1 prefetch (best measured across R13-R17 sweep:
// depth-2/4-per-CU/fusion all null or negative). Block (0,0) zeroes
// flag_cnt (replaces memset node).
// ---------------------------------------------------------------------------
__global__ __launch_bounds__(256) void k_gemm(const float* __restrict__ h,
                                              const float* __restrict__ w,
                                              float* __restrict__ part,
                                              int ks_len,
                                              int* __restrict__ flag_cnt) {
    __shared__ unsigned short LHS[2][2][128][40]; // [dbuf][hi/lo][tok][kpad] 40 KB
    __shared__ unsigned short LWS[2][2][64][40];  // 20 KB  => 60 KB total
    const int tid  = threadIdx.x;
    const int wv   = tid >> 6;
    const int lane = tid & 63;
    const int T0   = blockIdx.x * 128;
    const int k0   = blockIdx.y * ks_len;
    const int wr   = wv & 1;        // token half (64 tokens)
    const int wc   = wv >> 1;       // expert half (32 experts)
    const int lq   = lane >> 4;     // quarter 0..3
    const int lr   = lane & 15;
    const int koff = lq * 8;        // frag k-offset (bf16 elems)

    if (blockIdx.x == 0 && blockIdx.y == 0 && tid == 0) *flag_cnt = 0;

    const int hrow = tid & 127, hq = (tid >> 7) * 16;
    const int wrow = tid & 63,  wq = (tid >> 6) * 8;
    const float* gh = h + (size_t)(T0 + hrow) * D_MODEL + k0 + hq;
    const float* gw = w + (size_t)wrow * D_MODEL + k0 + wq;

    f32x4 acc[4][2];
#pragma unroll
    for (int i = 0; i < 4; ++i)
#pragma unroll
        for (int j = 0; j < 2; ++j)
#pragma unroll
            for (int x = 0; x < 4; ++x) acc[i][j][x] = 0.f;

    float4 h0, h1, h2, h3, w0, w1;      // prefetch regs (static names)
    auto gload = [&](int it) {
        const float* p = gh + it * 32;
        h0 = *(const float4*)(p);      h1 = *(const float4*)(p + 4);
        h2 = *(const float4*)(p + 8);  h3 = *(const float4*)(p + 12);
        const float* q = gw + it * 32;
        w0 = *(const float4*)(q);      w1 = *(const float4*)(q + 4);
    };
    auto writebuf = [&](int nb) {
        uint4 hi, lo;
        cvt8(h0, h1, hi, lo);
        *(uint4*)&LHS[nb][0][hrow][hq]     = hi;
        *(uint4*)&LHS[nb][1][hrow][hq]     = lo;
        cvt8(h2, h3, hi, lo);
        *(uint4*)&LHS[nb][0][hrow][hq + 8] = hi;
        *(uint4*)&LHS[nb][1][hrow][hq + 8] = lo;
        cvt8(w0, w1, hi, lo);
        *(uint4*)&LWS[nb][0][wrow][wq]     = hi;
        *(uint4*)&LWS[nb][1][wrow][wq]     = lo;
    };

    const int nt = ks_len >> 5;         // 16 tiles at KS=8
    gload(0);
    writebuf(0);
    __syncthreads();
    for (int it = 0; it < nt; ++it) {
        const int b = it & 1;
        if (it + 1 < nt) gload(it + 1);             // lands during MFMA phase
        const bf16x8 Bh0 = *(const bf16x8*)&LWS[b][0][wc * 32 + lr][koff];
        const bf16x8 Bl0 = *(const bf16x8*)&LWS[b][1][wc * 32 + lr][koff];
        const bf16x8 Bh1 = *(const bf16x8*)&LWS[b][0][wc * 32 + 16 + lr][koff];
        const bf16x8 Bl1 = *(const bf16x8*)&LWS[b][1][wc * 32 + 16 + lr][koff];
#pragma unroll
        for (int i4 = 0; i4 < 4; ++i4) {
            const bf16x8 Ah = *(const bf16x8*)&LHS[b][0][wr * 64 + i4 * 16 + lr][koff];
            const bf16x8 Al = *(const bf16x8*)&LHS[b][1][wr * 64 + i4 * 16 + lr][koff];
            acc[i4][0] = MFMA(Ah, Bh0, acc[i4][0]);
            acc[i4][1] = MFMA(Ah, Bh1, acc[i4][1]);
            acc[i4][0] = MFMA(Ah, Bl0, acc[i4][0]);
            acc[i4][1] = MFMA(Ah, Bl1, acc[i4][1]);
            acc[i4][0] = MFMA(Al, Bh0, acc[i4][0]);
            acc[i4][1] = MFMA(Al, Bh1, acc[i4][1]);
        }
        if (it + 1 < nt) writebuf(b ^ 1);           // vmcnt wait lands here
        __syncthreads();
    }

    // C/D layout (m89-verified): col = lane&15, row = (lane>>4)*4 + reg
    float* pb = part + (size_t)blockIdx.y * T_TOKENS * N_EXP;
#pragma unroll
    for (int i4 = 0; i4 < 4; ++i4)
#pragma unroll
        for (int j = 0; j < 2; ++j)
#pragma unroll
            for (int i = 0; i < 4; ++i) {
                const int t = T0 + wr * 64 + i4 * 16 + lq * 4 + i;
                const int e = wc * 32 + j * 16 + lr;
                pb[(size_t)t * N_EXP + e] = acc[i4][j][i];
            }
}

// ---------------------------------------------------------------------------
// Kernel 2: per-token softmax + top-8 + gap-based tie flagging + aux partials.
// block 256 (4 waves), wave handles 4 tokens, lane = expert. f32 throughout.
// ---------------------------------------------------------------------------
__global__ __launch_bounds__(256) void k_router(const float* __restrict__ part, int KS,
                                                float* __restrict__ out_idx,
                                                float* __restrict__ out_w,
                                                float* __restrict__ expsum,
                                                int* __restrict__ flag_cnt,
                                                int* __restrict__ flag_list) {
    __shared__ float laux[4][64];
    const int lane = threadIdx.x & 63;
    const int wid  = threadIdx.x >> 6;
    float aux_acc = 0.f;
    const int tbase = blockIdx.x * 16 + wid * 4;
    const size_t kstride = (size_t)T_TOKENS * N_EXP;

    for (int tt = 0; tt < 4; ++tt) {
        const int t = tbase + tt;
        const float* pb = part + (size_t)t * N_EXP + lane;
        float a0 = 0.f, a1 = 0.f, a2 = 0.f, a3 = 0.f;
        int ksi = 0;
        for (; ksi + 4 <= KS; ksi += 4) {
            a0 += pb[(size_t)(ksi + 0) * kstride];
            a1 += pb[(size_t)(ksi + 1) * kstride];
            a2 += pb[(size_t)(ksi + 2) * kstride];
            a3 += pb[(size_t)(ksi + 3) * kstride];
        }
        for (; ksi < KS; ++ksi) a0 += pb[(size_t)ksi * kstride];
        const float lg = (a0 + a1) + (a2 + a3);

        float m = lg;
#pragma unroll
        for (int off = 32; off; off >>= 1) m = fmaxf(m, __shfl_xor(m, off));
        const float p = __expf(lg - m);
        float s = p;
#pragma unroll
        for (int off = 32; off; off >>= 1) s += __shfl_xor(s, off);
        const float inv_s = 1.f / s;
        aux_acc += p * inv_s;

        float pv = lg; int pi = lane;
        float myp = 0.f; int myi = 0; float tsum = 0.f, prev = 0.f;
        bool flg = false;
#pragma unroll
        for (int r = 0; r < 9; ++r) {
            float bv = pv; int bi = pi;
#pragma unroll
            for (int off = 32; off; off >>= 1) {
                const float ov = __shfl_xor(bv, off);
                const int   oi = __shfl_xor(bi, off);
                if (ov > bv || (ov == bv && oi < bi)) { bv = ov; bi = oi; }
            }
            if (r > 0) flg = flg || (prev - bv < TAU);
            prev = bv;
            if (r < 8) {
                const float bp = __expf(bv - m) * inv_s;
                tsum += bp;
                if (lane == r)  { myp = bp; myi = bi; }
                if (lane == bi) pv = -1e30f;
            }
        }
        if (lane < 8) {
            out_idx[(size_t)t * 8 + lane] = (float)myi;
            out_w[(size_t)t * 8 + lane]   = myp / tsum;
        }
        if (lane == 0 && flg) {
            const int pos = atomicAdd(flag_cnt, 1);
            if (pos < T_TOKENS) flag_list[pos] = t;
        }
    }

    laux[wid][lane] = aux_acc;
    __syncthreads();
    if (threadIdx.x < 64)
        expsum[(size_t)blockIdx.x * 64 + threadIdx.x] =
            laux[0][threadIdx.x] + laux[1][threadIdx.x] +
            laux[2][threadIdx.x] + laux[3][threadIdx.x];
}

// ---------------------------------------------------------------------------
// Kernel 3: f64 repair (one block per flagged token) + FUSED aux finalize.
// ---------------------------------------------------------------------------
__global__ __launch_bounds__(256) void k_repair(const float* __restrict__ h,
                                                const float* __restrict__ w,
                                                const int* __restrict__ flag_cnt,
                                                const int* __restrict__ flag_list,
                                                float* __restrict__ out_idx,
                                                float* __restrict__ out_w,
                                                const float* __restrict__ expsum,
                                                int nb,
                                                float* __restrict__ out_aux) {
    __shared__ float  sh[D_MODEL];   // 16 KB
    __shared__ double sp[4][64];     //  2 KB
    __shared__ float  lx[4][64];     //  1 KB (aux)
    const int tid  = threadIdx.x;
    const int lane = tid & 63;
    const int c    = tid >> 6;

    if (blockIdx.x == 0) {           // fused aux finalize
        float s = 0.f;
        for (int b = c; b < nb; b += 4) s += expsum[(size_t)b * 64 + lane];
        lx[c][lane] = s;
        __syncthreads();
        if (tid < 64) {
            const float tot = lx[0][lane] + lx[1][lane] + lx[2][lane] + lx[3][lane];
            const float avg = tot * (1.f / (float)T_TOKENS);
            float v = avg * avg;
#pragma unroll
            for (int off = 32; off; off >>= 1) v += __shfl_xor(v, off);
            if (lane == 0) out_aux[0] = (float)N_EXP * 0.001f * v;
        }
    }

    const int n = min(*flag_cnt, T_TOKENS);
    for (int i = blockIdx.x; i < n; i += gridDim.x) {
        const int t = flag_list[i];
        __syncthreads();
#pragma unroll
        for (int q = 0; q < 4; ++q) {
            const int o = (q * 256 + tid) * 4;
            *reinterpret_cast<float4*>(&sh[o]) =
                *reinterpret_cast<const float4*>(&h[(size_t)t * D_MODEL + o]);
        }
        __syncthreads();

        const float* wp = &w[(size_t)lane * D_MODEL + c * 1024];
        const float* hp = &sh[c * 1024];
        double acc[8] = {0, 0, 0, 0, 0, 0, 0, 0};
        for (int q = 0; q < 32; ++q) {
            float4 wv8[8], hv8[8];
#pragma unroll
            for (int u = 0; u < 8; ++u) {
                wv8[u] = *reinterpret_cast<const float4*>(&wp[(q * 8 + u) * 4]);
                hv8[u] = *reinterpret_cast<const float4*>(&hp[(q * 8 + u) * 4]);
            }
#pragma unroll
            for (int u = 0; u < 8; ++u) {
                acc[u] = fma((double)hv8[u].x, (double)wv8[u].x, acc[u]);
                acc[u] = fma((double)hv8[u].y, (double)wv8[u].y, acc[u]);
                acc[u] = fma((double)hv8[u].z, (double)wv8[u].z, acc[u]);
                acc[u] = fma((double)hv8[u].w, (double)wv8[u].w, acc[u]);
            }
        }
        sp[c][lane] = (((acc[0] + acc[1]) + (acc[2] + acc[3])) +
                       ((acc[4] + acc[5]) + (acc[6] + acc[7])));
        __syncthreads();

        if (tid < 64) {
            const double mylg = ((sp[0][lane] + sp[1][lane]) +
                                 (sp[2][lane] + sp[3][lane]));
            double m = mylg;
#pragma unroll
            for (int off = 32; off; off >>= 1) m = fmax(m, __shfl_xor(m, off));
            double pv = mylg; int pi = lane;
            double myp = 0.0; int myi = 0; double tsum = 0.0;
#pragma unroll
            for (int r = 0; r < 8; ++r) {
                double bv = pv; int bi = pi;
#pragma unroll
                for (int off = 32; off; off >>= 1) {
                    const double ov = __shfl_xor(bv, off);
                    const int    oi = __shfl_xor(bi, off);
                    if (ov > bv || (ov == bv && oi < bi)) { bv = ov; bi = oi; }
                }
                const double bp = exp(bv - m);
                tsum += bp;
                if (lane == r)  { myp = bp; myi = bi; }
                if (lane == bi) pv = -1.0e300;
            }
            if (lane < 8) {
                out_idx[(size_t)t * 8 + lane] = (float)myi;
                out_w[(size_t)t * 8 + lane]   = (float)(myp / tsum);
            }
        }
    }
}

extern "C" void kernel_launch(void* const* d_in, const int* in_sizes, int n_in,
                              void* d_out, int out_size, void* d_ws, size_t ws_size,
                              hipStream_t stream) {
    const float* h = (const float*)d_in[0];   // [8192,4096]
    const float* w = (const float*)d_in[1];   // [64,4096]
    float* out      = (float*)d_out;
    float* out_idx  = out;                    // 65536 (indices as float)
    float* out_w    = out + 65536;            // 65536
    float* out_aux  = out + 131072;           // 1

    const size_t part_elems = (size_t)T_TOKENS * N_EXP;
    const int NB2 = 512;
    int KS = 8;                               // grid (64,8)=512 blocks = 2/CU
    while (KS > 1 &&
           ((size_t)KS * part_elems * 4 + (size_t)NB2 * 64 * 4 +
            4 + (size_t)T_TOKENS * 4) > ws_size)
        KS >>= 1;

    float* part     = (float*)d_ws;
    float* expsum   = part + (size_t)KS * part_elems;
    int*   flag_cnt = (int*)(expsum + (size_t)NB2 * 64);
    int*   flag_list= flag_cnt + 1;

    dim3 g1(T_TOKENS / 128, KS);
    k_gemm<<<g1, 256, 0, stream>>>(h, w, part, D_MODEL / KS, flag_cnt);
    k_router<<<NB2, 256, 0, stream>>>(part, KS, out_idx, out_w, expsum,
                                      flag_cnt, flag_list);
    k_repair<<<512, 256, 0, stream>>>(h, w, flag_cnt, flag_list, out_idx, out_w,
                                      expsum, NB2, out_aux);
}